// Round 1
// baseline (629.213 us; speedup 1.0000x reference)
//
#include <hip/hip_runtime.h>

// Pair feature expansion: out[(i*512+j)] = concat(x_i[0:260], x_j[0:260], r1, r2)
// n=512, d=260, out row = 522 floats (2088 B, 8B-aligned -> float2 vectorized).

#define NPAIR 512
#define DFEAT 260
#define ROW_OUT2 261   // 522 floats = 261 float2 per output row

__global__ __launch_bounds__(256) void pair_kernel(const float* __restrict__ in,
                                                   float* __restrict__ out) {
    const int p = blockIdx.x;            // pair index, 0..512*512-1
    const int i = p >> 9;                // row i
    const int j = p & (NPAIR - 1);       // row j

    const float* rowi = in + (size_t)i * DFEAT;
    const float* rowj = in + (size_t)j * DFEAT;

    // bbox coords live in the last 4 features (cols 256..259)
    const float x1i = rowi[256], y1i = rowi[257], x2i = rowi[258], y2i = rowi[259];
    const float x1j = rowj[256], y1j = rowj[257], x2j = rowj[258], y2j = rowj[259];

    float w = fminf(x2i, x2j) - fmaxf(x1i, x1j);
    float h = fminf(y2i, y2j) - fmaxf(y1i, y1j);
    w = fmaxf(w, 0.0f);
    h = fmaxf(h, 0.0f);
    const float inter = w * h;
    const float area_i = (x2i - x1i) * (y2i - y1i);
    const float area_j = (x2j - x1j) * (y2j - y1j);
    const float r1 = inter / area_i;
    const float r2 = inter / area_j;

    const float2* rowi2 = (const float2*)rowi;   // in row offset i*260 floats -> 8B aligned
    const float2* rowj2 = (const float2*)rowj;
    float2* orow = (float2*)(out + (size_t)p * 522);  // p*2088 bytes -> 8B aligned

    for (int t = threadIdx.x; t < ROW_OUT2; t += 256) {
        float2 v;
        if (t < 130) {
            v = rowi2[t];                 // x_i features 2t, 2t+1
        } else if (t < 260) {
            v = rowj2[t - 130];           // x_j features
        } else {
            v = make_float2(r1, r2);      // iou ratios
        }
        orow[t] = v;
    }
}

extern "C" void kernel_launch(void* const* d_in, const int* in_sizes, int n_in,
                              void* d_out, int out_size, void* d_ws, size_t ws_size,
                              hipStream_t stream) {
    const float* in = (const float*)d_in[0];
    float* out = (float*)d_out;
    pair_kernel<<<NPAIR * NPAIR, 256, 0, stream>>>(in, out);
}

// Round 2
// 583.180 us; speedup vs baseline: 1.0789x; 1.0789x over previous
//
#include <hip/hip_runtime.h>

// Pair feature expansion: out[i*512+j] = concat(x_i[0:260], x_j[0:260], r1, r2)
// n=512, d=260, out row = 522 floats. Output = 512^2 x 522 fp32 = 547 MB (write-bound).
//
// Structure: 4096 blocks = (i: 512) x (j-tile: 8 of 64). Each block owns a
// contiguous 64*522 = 33408-float (16B-aligned) output span -> flat float4
// stores, all lanes active. Values gathered from L2-resident input via
// per-component e/522 decomposition; r1/r2 per tile precomputed in LDS.

#define N 512
#define D 260
#define ROW 522
#define JT 64               // j-rows per block
#define SPAN (JT * ROW)     // 33408 floats per block
#define SPAN4 (SPAN / 4)    // 8352 float4 per block

__global__ __launch_bounds__(256) void pair_kernel(const float* __restrict__ in,
                                                   float* __restrict__ out) {
    const int bi = blockIdx.x;
    const int i  = bi >> 3;          // row i
    const int j0 = (bi & 7) * JT;    // j-tile base

    __shared__ float s_r1[JT];
    __shared__ float s_r2[JT];

    const int tid = threadIdx.x;

    // Phase 1: threads 0..63 compute IoU ratios for their j.
    if (tid < JT) {
        const float* bi_ = in + (size_t)i * D + 256;
        const float* bj_ = in + (size_t)(j0 + tid) * D + 256;
        const float x1i = bi_[0], y1i = bi_[1], x2i = bi_[2], y2i = bi_[3];
        const float x1j = bj_[0], y1j = bj_[1], x2j = bj_[2], y2j = bj_[3];
        float w = fminf(x2i, x2j) - fmaxf(x1i, x1j);
        float h = fminf(y2i, y2j) - fmaxf(y1i, y1j);
        w = fmaxf(w, 0.0f);
        h = fmaxf(h, 0.0f);
        const float inter  = w * h;
        const float area_i = (x2i - x1i) * (y2i - y1i);
        const float area_j = (x2j - x1j) * (y2j - y1j);
        s_r1[tid] = inter / area_i;
        s_r2[tid] = inter / area_j;
    }
    __syncthreads();

    const float* rowi = in + (size_t)i * D;
    float4* ospan = (float4*)(out + (size_t)bi * SPAN);  // bi*133632 B, 16B-aligned

    // Phase 2: flat float4 stores over the block's span.
    for (int f = tid; f < SPAN4; f += 256) {
        const int e0 = f * 4;
        float v[4];
#pragma unroll
        for (int k = 0; k < 4; ++k) {
            const unsigned e  = (unsigned)(e0 + k);
            const unsigned lj = e / 522u;          // local j row (magic mul)
            const unsigned c  = e - lj * 522u;     // column in output row
            float val;
            if (c < 260u) {
                val = rowi[c];                                   // x_i features
            } else if (c < 520u) {
                val = in[(size_t)(j0 + lj) * D + (c - 260u)];    // x_j features
            } else if (c == 520u) {
                val = s_r1[lj];
            } else {
                val = s_r2[lj];
            }
            v[k] = val;
        }
        ospan[f] = make_float4(v[0], v[1], v[2], v[3]);
    }
}

extern "C" void kernel_launch(void* const* d_in, const int* in_sizes, int n_in,
                              void* d_out, int out_size, void* d_ws, size_t ws_size,
                              hipStream_t stream) {
    const float* in = (const float*)d_in[0];
    float* out = (float*)d_out;
    pair_kernel<<<N * (N / JT), 256, 0, stream>>>(in, out);
}

// Round 3
// 536.682 us; speedup vs baseline: 1.1724x; 1.0866x over previous
//
#include <hip/hip_runtime.h>

// Pair feature expansion: out[i*512+j] = concat(x_i[0:260], x_j[0:260], r1, r2)
// n=512, d=260, out row = 522 floats (2088 B, 8B-aligned). Output 547 MB -> write-bound.
//
// Key insight (R2 post-mortem): vmcnt is a FIFO shared by global loads AND
// stores. Any global load consumed inside the store loop forces waitcnt that
// drains all earlier stores -> wave serializes on HBM store latency. Fix:
// phase 2 contains ONLY global stores; all sources come from registers or LDS
// (lgkmcnt, independent counter).
//
// Block = (i, 32-row j-tile). LDS: x_j tile 33280 B (+r1/r2) -> 4 blocks/CU.
// Wave w writes rows lj = w, w+4, ... Each 522-float row = 261 float2:
//   f2 g=lane      : x_i[2l..2l+1]          (per-lane regs, loaded once)
//   f2 g=64+lane   : x_i[128+2l..129+2l]    (regs)
//   f2 g=128+lane  : lanes 0,1 -> x_i bbox; lanes>=2 -> x_j f2[lane-2] (LDS)
//   f2 g=192+lane  : x_j f2[62+lane]        (LDS)
//   f2 g=256+l,l<5 : l<4 -> x_j f2[126+l]; l==4 -> (r1,r2)

#define N 512
#define D 260
#define JT 32

__global__ __launch_bounds__(256) void pair_kernel(const float* __restrict__ in,
                                                   float* __restrict__ out) {
    const int b    = blockIdx.x;
    const int i    = b >> 4;           // row i
    const int j0   = (b & 15) * JT;    // j-tile base
    const int tid  = threadIdx.x;
    const int lane = tid & 63;
    const int w    = tid >> 6;

    __shared__ float2 s_xj[JT * 130];  // 32 rows x 260 floats, flat f2 image
    __shared__ float  s_r1[JT], s_r2[JT];

    // Per-lane x_i registers (global loads BEFORE the store loop; waits here
    // are harmless — no stores issued yet).
    const float* rowi = in + i * D;
    const float2 xi_a = *(const float2*)(rowi + 2 * lane);        // x_i[2l..2l+1]
    const float2 xi_b = *(const float2*)(rowi + 128 + 2 * lane);  // x_i[128+2l..]
    const float4 bb   = *(const float4*)(rowi + 256);             // bbox (broadcast)

    // Stage x_j tile into LDS as a flat f2 copy. in + j0*260 is 8B-aligned.
    const float2* gj2 = (const float2*)(in + (size_t)j0 * D);
    for (int t = tid; t < JT * 130; t += 256) s_xj[t] = gj2[t];

    // IoU ratios for this (i, j-tile).
    if (tid < JT) {
        const float* bj = in + (size_t)(j0 + tid) * D + 256;
        const float x1j = bj[0], y1j = bj[1], x2j = bj[2], y2j = bj[3];
        const float x1i = bb.x, y1i = bb.y, x2i = bb.z, y2i = bb.w;
        float ww = fmaxf(0.0f, fminf(x2i, x2j) - fmaxf(x1i, x1j));
        float hh = fmaxf(0.0f, fminf(y2i, y2j) - fmaxf(y1i, y1j));
        const float inter = ww * hh;
        s_r1[tid] = inter / ((x2i - x1i) * (y2i - y1i));
        s_r2[tid] = inter / ((x2j - x1j) * (y2j - y1j));
    }
    __syncthreads();

    // Phase 2: pure store stream. No global loads -> stores fire-and-forget.
    for (int lj = w; lj < JT; lj += 4) {
        float2* ob = (float2*)(out + (size_t)(i * N + j0 + lj) * 522);
        const float2* xr = &s_xj[lj * 130];

        // g = 128+lane sources
        const int idx2 = (lane < 2) ? 0 : (lane - 2);
        float2 v2 = xr[idx2];
        if (lane == 0) v2 = make_float2(bb.x, bb.y);
        if (lane == 1) v2 = make_float2(bb.z, bb.w);
        const float2 v3 = xr[62 + lane];

        ob[lane]       = xi_a;
        ob[64 + lane]  = xi_b;
        ob[128 + lane] = v2;
        ob[192 + lane] = v3;
        if (lane < 5) {
            const float2 v4 = (lane < 4) ? xr[126 + ((lane < 4) ? lane : 3)]
                                         : make_float2(s_r1[lj], s_r2[lj]);
            ob[256 + lane] = v4;
        }
    }
}

extern "C" void kernel_launch(void* const* d_in, const int* in_sizes, int n_in,
                              void* d_out, int out_size, void* d_ws, size_t ws_size,
                              hipStream_t stream) {
    const float* in = (const float*)d_in[0];
    float* out = (float*)d_out;
    pair_kernel<<<N * (N / JT), 256, 0, stream>>>(in, out);
}